// Round 1
// baseline (443.947 us; speedup 1.0000x reference)
//
#include <hip/hip_runtime.h>
#include <math.h>

#define NB_B   2
#define NB_S   1024
#define NB_D   1024
#define NB_NH  8
#define NB_DQK 64
#define NB_DH  128
#define NB_BS  (NB_B*NB_S)   // 2048
#define NCH    8
#define CL     128           // chunk length

// ---------------- workspace offsets (in floats) ----------------
constexpr size_t OFF_Q   = 0;                               // [2048 x 512]
constexpr size_t OFF_K   = OFF_Q   + 2048ull*512;           // [2048 x 512]
constexpr size_t OFF_V   = OFF_K   + 2048ull*512;           // [2048 x 1024]
constexpr size_t OFF_XOG = OFF_V   + 2048ull*1024;          // [2048 x 1024]
constexpr size_t OFF_I   = OFF_XOG + 2048ull*1024;          // [16 x 1024]
constexpr size_t OFF_F   = OFF_I   + 16ull*1024;
constexpr size_t OFF_G   = OFF_F   + 16ull*1024;            // g_s
constexpr size_t OFF_GM  = OFF_G   + 16ull*1024;            // G_t (running max, >=0)
constexpr size_t OFF_DL  = OFF_GM  + 16ull*1024;            // Dloc [16][8][64*128]
constexpr size_t OFF_CB  = OFF_DL  + 16ull*8*8192;          // Cbefore [16][8][64*128]
constexpr size_t OFF_HNG = OFF_CB  + 16ull*8*8192;          // gated LN output [2048 x 1024]
constexpr size_t WS_FLOATS = OFF_HNG + 2048ull*1024;        // ~42.2 MB

// ---------------- generic 128x128x(K=1024) fp32 GEMM tile ----------------
__device__ __forceinline__ void gemm_tile_body(
    const float* __restrict__ A, const float* __restrict__ W,
    float* __restrict__ C, int ncols, int bm, int ctl)
{
  __shared__ float As[8][132];   // [kk][row], transposed A tile
  __shared__ float Bs[8][132];   // [kk][col]
  const int tid = threadIdx.x;
  const int tr = tid >> 4;       // 0..15 -> rows tr*8
  const int tc = tid & 15;       // cols tc*4 and tc*4+64
  float acc[8][8] = {};

  const int arow = tid >> 1, akq = tid & 1;   // A loader: row 0..127, half-quad
  const int bkr = tid >> 5, bcq = tid & 31;   // B loader: krow 0..7, col quad
  const float* Ap = A + (size_t)(bm*128 + arow)*NB_D + akq*4;
  const float* Bp = W + (size_t)bkr*ncols + ctl*128 + bcq*4;

  for (int kt = 0; kt < NB_D/8; ++kt) {
    float4 av = *(const float4*)(Ap + kt*8);
    float4 bv = *(const float4*)(Bp + (size_t)kt*8*ncols);
    __syncthreads();
    As[akq*4+0][arow]=av.x; As[akq*4+1][arow]=av.y;
    As[akq*4+2][arow]=av.z; As[akq*4+3][arow]=av.w;
    *(float4*)(&Bs[bkr][bcq*4]) = bv;
    __syncthreads();
    #pragma unroll
    for (int kk = 0; kk < 8; ++kk) {
      float a[8], b[8];
      *(float4*)(&a[0]) = *(const float4*)(&As[kk][tr*8]);
      *(float4*)(&a[4]) = *(const float4*)(&As[kk][tr*8+4]);
      *(float4*)(&b[0]) = *(const float4*)(&Bs[kk][tc*4]);
      *(float4*)(&b[4]) = *(const float4*)(&Bs[kk][tc*4+64]);
      #pragma unroll
      for (int u = 0; u < 8; ++u)
        #pragma unroll
        for (int x = 0; x < 8; ++x)
          acc[u][x] += a[u]*b[x];
    }
  }
  float* Cp = C + (size_t)(bm*128 + tr*8)*ncols + ctl*128;
  #pragma unroll
  for (int u = 0; u < 8; ++u) {
    float4 lo = {acc[u][0],acc[u][1],acc[u][2],acc[u][3]};
    float4 hi = {acc[u][4],acc[u][5],acc[u][6],acc[u][7]};
    *(float4*)(Cp + (size_t)u*ncols + tc*4)      = lo;
    *(float4*)(Cp + (size_t)u*ncols + tc*4 + 64) = hi;
  }
}

// q,k,v,xog projections fused into one grid (24 col-tiles x 16 row-tiles)
__global__ __launch_bounds__(256) void sgemm_proj(
    const float* __restrict__ x,
    const float* __restrict__ Wq, const float* __restrict__ Wk,
    const float* __restrict__ Wv, const float* __restrict__ Wog,
    float* __restrict__ q, float* __restrict__ k,
    float* __restrict__ v, float* __restrict__ xog)
{
  int ct = blockIdx.x, bm = blockIdx.y;
  const float* W; float* C; int ncols, ctl;
  if (ct < 4)       { W=Wq;  C=q;   ncols=512;  ctl=ct;    }
  else if (ct < 8)  { W=Wk;  C=k;   ncols=512;  ctl=ct-4;  }
  else if (ct < 16) { W=Wv;  C=v;   ncols=1024; ctl=ct-8;  }
  else              { W=Wog; C=xog; ncols=1024; ctl=ct-16; }
  gemm_tile_body(x, W, C, ncols, bm, ctl);
}

__global__ __launch_bounds__(256) void sgemm_out(
    const float* __restrict__ A, const float* __restrict__ W, float* __restrict__ C)
{
  gemm_tile_body(A, W, C, 1024, blockIdx.y, blockIdx.x);
}

// i/f projections (skinny N=8 each): one wave per row
__global__ __launch_bounds__(64) void proj_if(
    const float* __restrict__ x,
    const float* __restrict__ Wi, const float* __restrict__ bi,
    const float* __restrict__ Wf, const float* __restrict__ bf,
    float* __restrict__ iv, float* __restrict__ fv)
{
  const int row = blockIdx.x, l = threadIdx.x;
  const float* xr = x + (size_t)row*NB_D;
  float ai[8] = {}, af[8] = {};
  for (int p = 0; p < 16; ++p) {
    int kk = l + p*64;
    float xv = xr[kk];
    const float* wi = Wi + (size_t)kk*NB_NH;
    const float* wf = Wf + (size_t)kk*NB_NH;
    #pragma unroll
    for (int cc = 0; cc < 8; ++cc) { ai[cc] += xv*wi[cc]; af[cc] += xv*wf[cc]; }
  }
  #pragma unroll
  for (int off = 1; off < 64; off <<= 1) {
    #pragma unroll
    for (int cc = 0; cc < 8; ++cc) {
      ai[cc] += __shfl_xor(ai[cc], off);
      af[cc] += __shfl_xor(af[cc], off);
    }
  }
  if (l == 0) {
    int b = row >> 10, s = row & (NB_S-1);
    #pragma unroll
    for (int cc = 0; cc < 8; ++cc) {
      iv[(size_t)(b*NB_NH+cc)*NB_S + s] = ai[cc] + bi[cc];
      fv[(size_t)(b*NB_NH+cc)*NB_S + s] = af[cc] + bf[cc];
    }
  }
}

// gate scan per (b,h): b_t = cumsum(logsigmoid(f)); g = i - b; G = max(0, cummax g)
__global__ __launch_bounds__(64) void gate_scan(
    const float* __restrict__ iv, const float* __restrict__ fv,
    float* __restrict__ gv, float* __restrict__ Gv)
{
  const int bh = blockIdx.x, l = threadIdx.x;   // one wave, 16 elems/lane
  const int base = bh*NB_S + l*16;
  float fl[16];
  float run = 0.f;
  #pragma unroll
  for (int u = 0; u < 16; ++u) {
    float fr = fv[base + u];
    float flog = (fr >= 0.f) ? -log1pf(expf(-fr)) : (fr - log1pf(expf(fr)));
    run += flog; fl[u] = run;
  }
  float tot = run, sc = tot;
  #pragma unroll
  for (int off = 1; off < 64; off <<= 1) {
    float t = __shfl_up(sc, off);
    if (l >= off) sc += t;
  }
  float excl = sc - tot;
  float gm[16]; float rmax = -1e30f;
  #pragma unroll
  for (int u = 0; u < 16; ++u) {
    float bt = excl + fl[u];
    float g = iv[base + u] - bt;
    gv[base + u] = g;
    rmax = fmaxf(rmax, g); gm[u] = rmax;
  }
  float mx = rmax;
  #pragma unroll
  for (int off = 1; off < 64; off <<= 1) {
    float t = __shfl_up(mx, off);
    if (l >= off) mx = fmaxf(mx, t);
  }
  float em = __shfl_up(mx, 1);
  if (l == 0) em = -1e30f;
  #pragma unroll
  for (int u = 0; u < 16; ++u)
    Gv[base + u] = fmaxf(0.f, fmaxf(em, gm[u]));
}

// per-chunk local KV state: Dloc = sum_{s in chunk} exp(g_s - Gend_c) k_s v_s^T
__global__ __launch_bounds__(128) void chunk_local(
    const float* __restrict__ kb, const float* __restrict__ vb,
    const float* __restrict__ gv, const float* __restrict__ Gv,
    float* __restrict__ Dloc)
{
  __shared__ float ks[16][68];
  __shared__ float vs[16][132];
  __shared__ float ws[16];
  const int bx = blockIdx.x, bh = bx >> 3, c = bx & 7;
  const int b = bh >> 3, h = bh & 7;
  const int tid = threadIdx.x;
  const int rg = tid >> 3, cg = tid & 7;
  const int i0 = rg*4;
  float acc[4][16] = {};
  const float Gend = Gv[bh*NB_S + c*CL + CL-1];
  const float* kbp = kb + ((size_t)b*NB_S + c*CL)*(NB_NH*NB_DQK) + h*NB_DQK;
  const float* vbp = vb + ((size_t)b*NB_S + c*CL)*(NB_NH*NB_DH)  + h*NB_DH;
  const float* gbp = gv + bh*NB_S + c*CL;
  for (int sb = 0; sb < 8; ++sb) {
    __syncthreads();
    #pragma unroll
    for (int p = 0; p < 2; ++p) {
      int qd = tid + p*128; int r = qd >> 4, cq = qd & 15;
      *(float4*)(&ks[r][cq*4]) =
        *(const float4*)(kbp + (size_t)(sb*16 + r)*(NB_NH*NB_DQK) + cq*4);
    }
    #pragma unroll
    for (int p = 0; p < 4; ++p) {
      int qd = tid + p*128; int r = qd >> 5, cq = qd & 31;
      *(float4*)(&vs[r][cq*4]) =
        *(const float4*)(vbp + (size_t)(sb*16 + r)*(NB_NH*NB_DH) + cq*4);
    }
    if (tid < 16) ws[tid] = expf(gbp[sb*16 + tid] - Gend);
    __syncthreads();
    #pragma unroll
    for (int s = 0; s < 16; ++s) {
      float w = ws[s];
      float4 kq = *(const float4*)(&ks[s][i0]);
      float wk[4] = {w*kq.x, w*kq.y, w*kq.z, w*kq.w};
      #pragma unroll
      for (int m = 0; m < 4; ++m) {
        float4 vq = *(const float4*)(&vs[s][cg*4 + m*32]);
        #pragma unroll
        for (int u = 0; u < 4; ++u) {
          acc[u][m*4+0] += wk[u]*vq.x;
          acc[u][m*4+1] += wk[u]*vq.y;
          acc[u][m*4+2] += wk[u]*vq.z;
          acc[u][m*4+3] += wk[u]*vq.w;
        }
      }
    }
  }
  float* dst = Dloc + ((size_t)bh*NCH + c)*(NB_DQK*NB_DH);
  #pragma unroll
  for (int u = 0; u < 4; ++u)
    #pragma unroll
    for (int m = 0; m < 4; ++m) {
      float4 o4 = {acc[u][m*4+0],acc[u][m*4+1],acc[u][m*4+2],acc[u][m*4+3]};
      *(float4*)(dst + (size_t)(i0+u)*NB_DH + cg*4 + m*32) = o4;
    }
}

// sequential combine over 8 chunks: Cbefore[c] = state before chunk c (ref Gend_{c-1})
__global__ __launch_bounds__(256) void chunk_combine(
    const float* __restrict__ Dloc, const float* __restrict__ Gv,
    float* __restrict__ Cbef)
{
  const int bh = blockIdx.x, tid = threadIdx.x;
  float4 acc[8];
  #pragma unroll
  for (int p = 0; p < 8; ++p) acc[p] = float4{0.f,0.f,0.f,0.f};
  float Gprev = 0.f;
  for (int c = 0; c < NCH; ++c) {
    const float4* dl = (const float4*)(Dloc + ((size_t)bh*NCH + c)*8192);
    float4* cb = (float4*)(Cbef + ((size_t)bh*NCH + c)*8192);
    float Gend = Gv[bh*NB_S + c*CL + CL-1];
    float decay = (c == 0) ? 0.f : expf(Gprev - Gend);
    #pragma unroll
    for (int p = 0; p < 8; ++p) {
      int idx = tid + p*256;
      cb[idx] = acc[p];
      float4 d = dl[idx];
      acc[p].x = acc[p].x*decay + d.x;
      acc[p].y = acc[p].y*decay + d.y;
      acc[p].z = acc[p].z*decay + d.z;
      acc[p].w = acc[p].w*decay + d.w;
    }
    Gprev = Gend;
  }
}

// chunked attention + state term + LayerNorm + output gate -> hng
__global__ __launch_bounds__(256,1) void chunk_out(
    const float* __restrict__ qb, const float* __restrict__ kb,
    const float* __restrict__ vb, const float* __restrict__ xog,
    const float* __restrict__ gv, const float* __restrict__ Gv,
    const float* __restrict__ Cbef,
    const float* __restrict__ lnw, const float* __restrict__ lnb,
    float* __restrict__ hng)
{
  __shared__ float attT[128][132];  // attT[s][t]
  __shared__ float buf[128][132];   // A: rows0-63 Q^T[i][t], rows64-127 K^T[i][s];
                                    // B1: rows64-127 Cb[i][j]; B2: V[s][j]
  __shared__ float gsh[128], Gsh[128], rsh[128];

  const int bx = blockIdx.x, bh = bx >> 3, c = bx & 7;
  const int b = bh >> 3, h = bh & 7;
  const int tid = threadIdx.x;
  const int tr = tid >> 4, tc = tid & 15;
  const int t0 = tr*8;
  const size_t rowbase = (size_t)b*NB_S + (size_t)c*CL;
  const int sgbase = bh*NB_S + c*CL;

  #pragma unroll
  for (int p = 0; p < 8; ++p) {
    int qd = tid + p*256;
    int t = qd >> 4, iq = qd & 15;
    float4 q4 = *(const float4*)(qb + (rowbase + t)*(NB_NH*NB_DQK) + h*NB_DQK + iq*4);
    buf[iq*4+0][t]=q4.x; buf[iq*4+1][t]=q4.y; buf[iq*4+2][t]=q4.z; buf[iq*4+3][t]=q4.w;
    float4 k4 = *(const float4*)(kb + (rowbase + t)*(NB_NH*NB_DQK) + h*NB_DQK + iq*4);
    buf[64+iq*4+0][t]=k4.x; buf[64+iq*4+1][t]=k4.y; buf[64+iq*4+2][t]=k4.z; buf[64+iq*4+3][t]=k4.w;
  }
  if (tid < 128) {
    float gval = gv[sgbase + tid];
    float Gval = Gv[sgbase + tid];
    gsh[tid] = gval; Gsh[tid] = Gval;
    float Gprev = (c > 0) ? Gv[sgbase - 1] : 0.f;
    rsh[tid] = 0.125f * expf(Gprev - Gval);
  }
  __syncthreads();

  auto mm = [&](float (&accR)[8][8], float (*Am)[132], int ar0,
                float (*Bm)[132], int br0, int nq) {
    for (int iq = 0; iq < nq; ++iq) {
      float a[4][8], bq[4][8];
      #pragma unroll
      for (int w = 0; w < 4; ++w) {
        const float* ap = Am[ar0 + iq*4 + w];
        *(float4*)(&a[w][0]) = *(const float4*)(ap + t0);
        *(float4*)(&a[w][4]) = *(const float4*)(ap + t0 + 4);
        const float* bp = Bm[br0 + iq*4 + w];
        *(float4*)(&bq[w][0]) = *(const float4*)(bp + tc*4);
        *(float4*)(&bq[w][4]) = *(const float4*)(bp + tc*4 + 64);
      }
      #pragma unroll
      for (int w = 0; w < 4; ++w)
        #pragma unroll
        for (int u = 0; u < 8; ++u)
          #pragma unroll
          for (int x = 0; x < 8; ++x)
            accR[u][x] += a[w][u]*bq[w][x];
    }
  };

  { // phase A: att = Q K^T, weight, mask, store transposed
    float accA[8][8] = {};
    mm(accA, buf, 0, buf, 64, 16);
    float gtv[8];
    #pragma unroll
    for (int u = 0; u < 8; ++u) gtv[u] = Gsh[t0 + u];
    #pragma unroll
    for (int x = 0; x < 8; ++x) {
      int s = tc*4 + (x>>2)*64 + (x&3);
      float gs = gsh[s];
      float vv[8];
      #pragma unroll
      for (int u = 0; u < 8; ++u) {
        int t = t0 + u;
        float w = 0.125f * expf(gs - gtv[u]);
        vv[u] = (s <= t) ? accA[u][x]*w : 0.f;
      }
      float4 lo = {vv[0],vv[1],vv[2],vv[3]}, hi = {vv[4],vv[5],vv[6],vv[7]};
      *(float4*)(&attT[s][t0])   = lo;
      *(float4*)(&attT[s][t0+4]) = hi;
    }
  }
  __syncthreads();

  { // load Cbefore into buf rows 64..127 (K^T dead, Q^T alive)
    const float* Cbp = Cbef + ((size_t)bh*NCH + c)*(NB_DQK*NB_DH);
    #pragma unroll
    for (int p = 0; p < 8; ++p) {
      int qd = tid + p*256;
      int i = qd >> 5, jq = qd & 31;
      *(float4*)(&buf[64+i][jq*4]) = *(const float4*)(Cbp + (size_t)i*NB_DH + jq*4);
    }
  }
  __syncthreads();
  float acc2[8][8] = {};
  mm(acc2, buf, 0, buf, 64, 16);       // state term: Q * Cbefore
  __syncthreads();

  { // load V into buf (all rows)
    #pragma unroll
    for (int p = 0; p < 16; ++p) {
      int qd = tid + p*256;
      int sv = qd >> 5, jq = qd & 31;
      *(float4*)(&buf[sv][jq*4]) =
        *(const float4*)(vb + (rowbase + sv)*(NB_NH*NB_DH) + h*NB_DH + jq*4);
    }
  }
  __syncthreads();
  float hacc[8][8] = {};
  mm(hacc, attT, 0, buf, 0, 32);       // intra-chunk: att * V

  // epilogue: combine, LayerNorm, output gate, store
  float lw[8], lb[8];
  {
    float4 a0 = *(const float4*)(lnw + h*NB_DH + tc*4);
    float4 a1 = *(const float4*)(lnw + h*NB_DH + tc*4 + 64);
    lw[0]=a0.x; lw[1]=a0.y; lw[2]=a0.z; lw[3]=a0.w;
    lw[4]=a1.x; lw[5]=a1.y; lw[6]=a1.z; lw[7]=a1.w;
    float4 b0 = *(const float4*)(lnb + h*NB_DH + tc*4);
    float4 b1 = *(const float4*)(lnb + h*NB_DH + tc*4 + 64);
    lb[0]=b0.x; lb[1]=b0.y; lb[2]=b0.z; lb[3]=b0.w;
    lb[4]=b1.x; lb[5]=b1.y; lb[6]=b1.z; lb[7]=b1.w;
  }
  #pragma unroll
  for (int u = 0; u < 8; ++u) {
    int t = t0 + u;
    float r = rsh[t];
    float hrow[8];
    #pragma unroll
    for (int x = 0; x < 8; ++x) hrow[x] = hacc[u][x] + r*acc2[u][x];
    float sum = 0.f, ssq = 0.f;
    #pragma unroll
    for (int x = 0; x < 8; ++x) { sum += hrow[x]; ssq += hrow[x]*hrow[x]; }
    #pragma unroll
    for (int off = 1; off < 16; off <<= 1) {
      sum += __shfl_xor(sum, off);
      ssq += __shfl_xor(ssq, off);
    }
    float mean = sum * (1.f/NB_DH);
    float var  = ssq * (1.f/NB_DH) - mean*mean;
    float rstd = rsqrtf(var + 1e-6f);
    #pragma unroll
    for (int m = 0; m < 2; ++m) {
      float4 xo = *(const float4*)(xog + (rowbase + t)*NB_D + h*NB_DH + tc*4 + m*64);
      float xov[4] = {xo.x, xo.y, xo.z, xo.w};
      float res[4];
      #pragma unroll
      for (int w = 0; w < 4; ++w) {
        int x = m*4 + w;
        float hn = (hrow[x] - mean)*rstd*lw[x] + lb[x];
        float tt = tanhf(xov[w]*(1.f/15.f))*15.f;
        float o = 1.f/(1.f + expf(-tt));
        res[w] = hn*o;
      }
      float4 r4 = {res[0],res[1],res[2],res[3]};
      *(float4*)(hng + (rowbase + t)*NB_D + h*NB_DH + tc*4 + m*64) = r4;
    }
  }
}

extern "C" void kernel_launch(void* const* d_in, const int* in_sizes, int n_in,
                              void* d_out, int out_size, void* d_ws, size_t ws_size,
                              hipStream_t stream)
{
  (void)in_sizes; (void)n_in; (void)out_size; (void)ws_size;
  const float* x   = (const float*)d_in[0];
  const float* Wq  = (const float*)d_in[1];
  const float* Wk  = (const float*)d_in[2];
  const float* Wv  = (const float*)d_in[3];
  const float* Wi  = (const float*)d_in[4];
  const float* bi  = (const float*)d_in[5];
  const float* Wf  = (const float*)d_in[6];
  const float* bf  = (const float*)d_in[7];
  const float* Wog = (const float*)d_in[8];
  const float* lnw = (const float*)d_in[9];
  const float* lnb = (const float*)d_in[10];
  const float* Wout= (const float*)d_in[11];
  float* out = (float*)d_out;
  float* ws  = (float*)d_ws;

  float* q   = ws + OFF_Q;
  float* k   = ws + OFF_K;
  float* v   = ws + OFF_V;
  float* xog = ws + OFF_XOG;
  float* iv  = ws + OFF_I;
  float* fv  = ws + OFF_F;
  float* g   = ws + OFF_G;
  float* G   = ws + OFF_GM;
  float* Dl  = ws + OFF_DL;
  float* Cb  = ws + OFF_CB;
  float* hng = ws + OFF_HNG;

  sgemm_proj<<<dim3(24,16), 256, 0, stream>>>(x, Wq, Wk, Wv, Wog, q, k, v, xog);
  proj_if<<<2048, 64, 0, stream>>>(x, Wi, bi, Wf, bf, iv, fv);
  gate_scan<<<16, 64, 0, stream>>>(iv, fv, g, G);
  chunk_local<<<128, 128, 0, stream>>>(k, v, g, G, Dl);
  chunk_combine<<<16, 256, 0, stream>>>(Dl, G, Cb);
  chunk_out<<<128, 256, 0, stream>>>(q, k, v, xog, g, G, Cb, lnw, lnb, hng);
  sgemm_out<<<dim3(8,16), 256, 0, stream>>>(hng, Wout, out);
}

// Round 4
// 200.331 us; speedup vs baseline: 2.2161x; 2.2161x over previous
//
#include <hip/hip_runtime.h>
#include <math.h>

#define NB_B   2
#define NB_S   1024
#define NB_D   1024
#define NB_NH  8
#define NB_DQK 64
#define NB_DH  128
#define NCH    8
#define CL     128
#define LDP    3072   // combined projection buffer row stride (q|k|v|xog)

typedef __attribute__((ext_vector_type(8))) short  short8v;   // 8 x bf16
typedef __attribute__((ext_vector_type(4))) float  f32x4;
typedef __attribute__((ext_vector_type(8))) unsigned short ushort8v;
typedef __attribute__((ext_vector_type(4))) unsigned short ushort4v;

__device__ __forceinline__ unsigned short f2bf(float f) {
  unsigned u = __float_as_uint(f);
  unsigned r = (u + 0x7FFFu + ((u >> 16) & 1u)) >> 16;
  return (unsigned short)r;
}
__device__ __forceinline__ float bf2f(unsigned short h) {
  return __uint_as_float(((unsigned)h) << 16);
}

#define GLD_LDS16(g, l) __builtin_amdgcn_global_load_lds( \
    (const __attribute__((address_space(1))) void*)(g),   \
    (__attribute__((address_space(3))) void*)(l), 16, 0, 0)

// ---------------- workspace offsets (floats) ----------------
// bf16 sizes: elems/2 floats. xh/xl: 2048*1024 bf16 = 1,048,576 floats EACH.
constexpr size_t OFF_P   = 0;                           // P fp32 [2048][3072] = 6,291,456
constexpr size_t OFF_XH  = OFF_P   + 2048ull*3072;      // xh bf16 [2048][1024] -> 1,048,576 f
constexpr size_t OFF_XL  = OFF_XH  + 1048576;           // xl bf16 [2048][1024] -> 1,048,576 f
constexpr size_t OFF_WHI = OFF_XL  + 1048576;           // Whi bf16 [3072][1024] -> 1,572,864 f
constexpr size_t OFF_WLO = OFF_WHI + 1572864;           // Wlo bf16 [1024][1024] -> 524,288 f
constexpr size_t OFF_IV  = OFF_WLO + 524288;
constexpr size_t OFF_FV  = OFF_IV  + 16384;
constexpr size_t OFF_G   = OFF_FV  + 16384;
constexpr size_t OFF_GM  = OFF_G   + 16384;
// total: OFF_GM + 16384 = 10,551,296 floats = 42.2 MB (== round-1 proven footprint)
// aliases (regions dead after gemm_proj):
constexpr size_t OFF_DL  = OFF_XH;                      // Dloc fp32 1,048,576 f (== xh size)
constexpr size_t OFF_HNG = OFF_XL;                      // hng bf16 [2048][1024] = 1,048,576 f (== xl size)
constexpr size_t OFF_CB  = OFF_WHI;                     // Cbef fp32 1,048,576 f (<= Whi's 1,572,864)
constexpr size_t OFF_WTO = OFF_WLO;                     // WtO bf16 [1024][1024] = 524,288 f (== Wlo size)

// ---------------- fp32 -> (hi,lo) bf16 split ----------------
__global__ __launch_bounds__(256) void conv_split(
    const float* __restrict__ src,
    unsigned short* __restrict__ hi, unsigned short* __restrict__ lo, int n)
{
  int i = (blockIdx.x * 256 + threadIdx.x) * 8;
  if (i >= n) return;
  float4 a = *(const float4*)(src + i);
  float4 b = *(const float4*)(src + i + 4);
  float v[8] = { a.x, a.y, a.z, a.w, b.x, b.y, b.z, b.w };
  ushort8v rh, rl;
  #pragma unroll
  for (int j = 0; j < 8; ++j) {
    unsigned short h = f2bf(v[j]);
    rh[j] = h;
    rl[j] = f2bf(v[j] - bf2f(h));
  }
  *(ushort8v*)(hi + i) = rh;
  *(ushort8v*)(lo + i) = rl;
}

// ---------------- transpose + convert: src fp32 [1024][N] -> hi/lo bf16 [N][1024] ----------------
__global__ __launch_bounds__(256) void transp_hl(
    const float* __restrict__ src,
    unsigned short* __restrict__ hi, unsigned short* __restrict__ lo, int N)
{
  __shared__ float Ls[64][65];
  const int nt = blockIdx.x, kt = blockIdx.y, tid = threadIdx.x;
  #pragma unroll
  for (int p = 0; p < 16; ++p) {
    int lin = p * 256 + tid;
    int kr = lin >> 6, nc = lin & 63;
    Ls[kr][nc] = src[(size_t)(kt*64 + kr) * N + nt*64 + nc];
  }
  __syncthreads();
  #pragma unroll
  for (int p = 0; p < 16; ++p) {
    int lin = p * 256 + tid;
    int nr = lin >> 6, kc = lin & 63;
    float v = Ls[kc][nr];
    unsigned short h = f2bf(v);
    size_t di = (size_t)(nt*64 + nr) * 1024 + kt*64 + kc;
    hi[di] = h;
    if (lo) lo[di] = f2bf(v - bf2f(h));
  }
}

// ---------------- fused projection GEMM (split-bf16 for q,k columns) ----------------
// P[2048][3072] = x[2048][1024] * W[1024][3072]; col-tiles ct<8 (q,k) use 3 phases:
// xh*Whi + xl*Whi + xh*Wlo; ct>=8 (v,xog) use 1 phase (xh*Whi).
__global__ __launch_bounds__(256) void gemm_proj(
    const unsigned short* __restrict__ xh,
    const unsigned short* __restrict__ xl,
    const unsigned short* __restrict__ Whi,
    const unsigned short* __restrict__ Wlo,
    float* __restrict__ P)
{
  __shared__ __align__(16) unsigned short As[128*64];
  __shared__ __align__(16) unsigned short Bs[128*64];
  const int tid  = threadIdx.x;
  const int ct   = blockIdx.x, bm = blockIdx.y;
  const int wid  = tid >> 6, lane = tid & 63;
  const int wm   = wid >> 1, wn = wid & 1;
  const int lrow = lane & 15;
  const int lk   = (lane >> 4) * 16;

  f32x4 acc[4][4];
  const f32x4 z4 = { 0.f, 0.f, 0.f, 0.f };
  #pragma unroll
  for (int m = 0; m < 4; ++m)
    #pragma unroll
    for (int n = 0; n < 4; ++n) acc[m][n] = z4;

  const int srow = tid >> 3;
  const int scb  = (tid & 7) << 4;
  size_t gAo[4], gBo[4];
  #pragma unroll
  for (int i = 0; i < 4; ++i) {
    int row = i * 32 + srow;
    int cbs = scb ^ ((row & 7) << 4);
    gAo[i] = (size_t)(bm*128 + row) * 2048 + cbs;   // x row stride 1024*2 B
    gBo[i] = (size_t)row * 2048 + cbs;              // W rows relative to tile base
  }
  const int ldsW = wid * 1024;

  const char* Aph[3] = { (const char*)xh, (const char*)xl, (const char*)xh };
  const char* Bhi  = (const char*)(Whi + (size_t)ct*128*1024);
  const char* Bph[3] = { Bhi, Bhi, (const char*)(Wlo + (size_t)ct*128*1024) };
  const int nph = (ct < 8) ? 3 : 1;

  for (int ph = 0; ph < nph; ++ph) {
    const char* Ab = Aph[ph];
    const char* Bb = Bph[ph];
    for (int kt = 0; kt < 16; ++kt) {
      __syncthreads();
      #pragma unroll
      for (int i = 0; i < 4; ++i)
        GLD_LDS16(Ab + gAo[i] + kt*128, (char*)As + i*4096 + ldsW);
      #pragma unroll
      for (int i = 0; i < 4; ++i)
        GLD_LDS16(Bb + gBo[i] + kt*128, (char*)Bs + i*4096 + ldsW);
      __syncthreads();

      #pragma unroll
      for (int kk = 0; kk < 2; ++kk) {
        short8v a[4], b[4];
        #pragma unroll
        for (int m = 0; m < 4; ++m) {
          int row = wm*64 + m*16 + lrow;
          int kb  = (kk*64 + lk) ^ ((row & 7) << 4);
          a[m] = *(const short8v*)((const char*)As + row*128 + kb);
        }
        #pragma unroll
        for (int n = 0; n < 4; ++n) {
          int row = wn*64 + n*16 + lrow;
          int kb  = (kk*64 + lk) ^ ((row & 7) << 4);
          b[n] = *(const short8v*)((const char*)Bs + row*128 + kb);
        }
        #pragma unroll
        for (int m = 0; m < 4; ++m)
          #pragma unroll
          for (int n = 0; n < 4; ++n)
            acc[m][n] = __builtin_amdgcn_mfma_f32_16x16x32_bf16(a[m], b[n], acc[m][n], 0, 0, 0);
      }
    }
  }

  const int crow0 = bm*128 + wm*64 + ((lane >> 4) << 2);
  const int ccol0 = ct*128 + wn*64 + (lane & 15);
  #pragma unroll
  for (int m = 0; m < 4; ++m)
    #pragma unroll
    for (int n = 0; n < 4; ++n)
      #pragma unroll
      for (int r = 0; r < 4; ++r)
        P[(size_t)(crow0 + m*16 + r) * LDP + ccol0 + n*16] = acc[m][n][r];
}

// ---------------- plain bf16 GEMM (output projection) ----------------
__global__ __launch_bounds__(256) void gemm_bf16(
    const unsigned short* __restrict__ A,
    const unsigned short* __restrict__ Bt,
    float* __restrict__ C, int ldc)
{
  __shared__ __align__(16) unsigned short As[128*64];
  __shared__ __align__(16) unsigned short Bs[128*64];
  const int tid  = threadIdx.x;
  const int bm   = blockIdx.y, cn = blockIdx.x;
  const int wid  = tid >> 6, lane = tid & 63;
  const int wm   = wid >> 1, wn = wid & 1;
  const int lrow = lane & 15;
  const int lk   = (lane >> 4) * 16;

  f32x4 acc[4][4];
  const f32x4 z4 = { 0.f, 0.f, 0.f, 0.f };
  #pragma unroll
  for (int m = 0; m < 4; ++m)
    #pragma unroll
    for (int n = 0; n < 4; ++n) acc[m][n] = z4;

  const int srow = tid >> 3;
  const int scb  = (tid & 7) << 4;
  const char* Ab = (const char*)A;
  const char* Bb = (const char*)Bt;
  size_t gA[4], gB[4];
  #pragma unroll
  for (int i = 0; i < 4; ++i) {
    int row = i * 32 + srow;
    int cbs = scb ^ ((row & 7) << 4);
    gA[i] = (size_t)(bm*128 + row) * 2048 + cbs;
    gB[i] = (size_t)(cn*128 + row) * 2048 + cbs;
  }
  const int ldsW = wid * 1024;

  for (int kt = 0; kt < 16; ++kt) {
    __syncthreads();
    #pragma unroll
    for (int i = 0; i < 4; ++i)
      GLD_LDS16(Ab + gA[i] + kt*128, (char*)As + i*4096 + ldsW);
    #pragma unroll
    for (int i = 0; i < 4; ++i)
      GLD_LDS16(Bb + gB[i] + kt*128, (char*)Bs + i*4096 + ldsW);
    __syncthreads();

    #pragma unroll
    for (int kk = 0; kk < 2; ++kk) {
      short8v a[4], b[4];
      #pragma unroll
      for (int m = 0; m < 4; ++m) {
        int row = wm*64 + m*16 + lrow;
        int kb  = (kk*64 + lk) ^ ((row & 7) << 4);
        a[m] = *(const short8v*)((const char*)As + row*128 + kb);
      }
      #pragma unroll
      for (int n = 0; n < 4; ++n) {
        int row = wn*64 + n*16 + lrow;
        int kb  = (kk*64 + lk) ^ ((row & 7) << 4);
        b[n] = *(const short8v*)((const char*)Bs + row*128 + kb);
      }
      #pragma unroll
      for (int m = 0; m < 4; ++m)
        #pragma unroll
        for (int n = 0; n < 4; ++n)
          acc[m][n] = __builtin_amdgcn_mfma_f32_16x16x32_bf16(a[m], b[n], acc[m][n], 0, 0, 0);
    }
  }

  const int crow0 = bm*128 + wm*64 + ((lane >> 4) << 2);
  const int ccol0 = cn*128 + wn*64 + (lane & 15);
  #pragma unroll
  for (int m = 0; m < 4; ++m)
    #pragma unroll
    for (int n = 0; n < 4; ++n)
      #pragma unroll
      for (int r = 0; r < 4; ++r)
        C[(size_t)(crow0 + m*16 + r) * ldc + ccol0 + n*16] = acc[m][n][r];
}

// ---------------- i/f projections (fp32, skinny N=8) ----------------
__global__ __launch_bounds__(64) void proj_if(
    const float* __restrict__ x,
    const float* __restrict__ Wi, const float* __restrict__ bi,
    const float* __restrict__ Wf, const float* __restrict__ bf,
    float* __restrict__ iv, float* __restrict__ fv)
{
  const int row = blockIdx.x, l = threadIdx.x;
  const float* xr = x + (size_t)row * NB_D;
  float ai[8] = {}, af[8] = {};
  for (int p = 0; p < 16; ++p) {
    int kk = l + p * 64;
    float xv = xr[kk];
    const float* wi = Wi + (size_t)kk * NB_NH;
    const float* wf = Wf + (size_t)kk * NB_NH;
    #pragma unroll
    for (int cc = 0; cc < 8; ++cc) { ai[cc] += xv*wi[cc]; af[cc] += xv*wf[cc]; }
  }
  #pragma unroll
  for (int off = 1; off < 64; off <<= 1) {
    #pragma unroll
    for (int cc = 0; cc < 8; ++cc) {
      ai[cc] += __shfl_xor(ai[cc], off);
      af[cc] += __shfl_xor(af[cc], off);
    }
  }
  if (l == 0) {
    int b = row >> 10, s = row & (NB_S - 1);
    #pragma unroll
    for (int cc = 0; cc < 8; ++cc) {
      iv[(size_t)(b*NB_NH + cc) * NB_S + s] = ai[cc] + bi[cc];
      fv[(size_t)(b*NB_NH + cc) * NB_S + s] = af[cc] + bf[cc];
    }
  }
}

// ---------------- gate scan ----------------
__global__ __launch_bounds__(64) void gate_scan(
    const float* __restrict__ iv, const float* __restrict__ fv,
    float* __restrict__ gv, float* __restrict__ Gv)
{
  const int bh = blockIdx.x, l = threadIdx.x;
  const int base = bh * NB_S + l * 16;
  float fl[16];
  float run = 0.f;
  #pragma unroll
  for (int u = 0; u < 16; ++u) {
    float fr = fv[base + u];
    float flog = (fr >= 0.f) ? -log1pf(expf(-fr)) : (fr - log1pf(expf(fr)));
    run += flog; fl[u] = run;
  }
  float tot = run, sc = tot;
  #pragma unroll
  for (int off = 1; off < 64; off <<= 1) {
    float t = __shfl_up(sc, off);
    if (l >= off) sc += t;
  }
  float excl = sc - tot;
  float gm[16]; float rmax = -1e30f;
  #pragma unroll
  for (int u = 0; u < 16; ++u) {
    float bt = excl + fl[u];
    float g = iv[base + u] - bt;
    gv[base + u] = g;
    rmax = fmaxf(rmax, g); gm[u] = rmax;
  }
  float mx = rmax;
  #pragma unroll
  for (int off = 1; off < 64; off <<= 1) {
    float t = __shfl_up(mx, off);
    if (l >= off) mx = fmaxf(mx, t);
  }
  float em = __shfl_up(mx, 1);
  if (l == 0) em = -1e30f;
  #pragma unroll
  for (int u = 0; u < 16; ++u)
    Gv[base + u] = fmaxf(0.f, fmaxf(em, gm[u]));
}

// ---------------- per-chunk local KV state ----------------
__global__ __launch_bounds__(128) void chunk_local(
    const float* __restrict__ P,
    const float* __restrict__ gv, const float* __restrict__ Gv,
    float* __restrict__ Dloc)
{
  __shared__ float ks[16][68];
  __shared__ float vs[16][132];
  __shared__ float wsg[16];
  const int bx = blockIdx.x, bh = bx >> 3, c = bx & 7;
  const int b = bh >> 3, h = bh & 7;
  const int tid = threadIdx.x;
  const int rg = tid >> 3, cg = tid & 7;
  const int i0 = rg * 4;
  float acc[4][16] = {};
  const float Gend = Gv[bh*NB_S + c*CL + CL - 1];
  const float* kbp = P + ((size_t)b*NB_S + c*CL) * LDP + 512  + h*NB_DQK;
  const float* vbp = P + ((size_t)b*NB_S + c*CL) * LDP + 1024 + h*NB_DH;
  const float* gbp = gv + bh*NB_S + c*CL;
  for (int sb = 0; sb < 8; ++sb) {
    __syncthreads();
    #pragma unroll
    for (int p = 0; p < 2; ++p) {
      int qd = tid + p*128; int r = qd >> 4, cq = qd & 15;
      *(float4*)(&ks[r][cq*4]) = *(const float4*)(kbp + (size_t)(sb*16 + r)*LDP + cq*4);
    }
    #pragma unroll
    for (int p = 0; p < 4; ++p) {
      int qd = tid + p*128; int r = qd >> 5, cq = qd & 31;
      *(float4*)(&vs[r][cq*4]) = *(const float4*)(vbp + (size_t)(sb*16 + r)*LDP + cq*4);
    }
    if (tid < 16) wsg[tid] = expf(gbp[sb*16 + tid] - Gend);
    __syncthreads();
    #pragma unroll
    for (int s = 0; s < 16; ++s) {
      float w = wsg[s];
      float4 kq = *(const float4*)(&ks[s][i0]);
      float wk[4] = { w*kq.x, w*kq.y, w*kq.z, w*kq.w };
      #pragma unroll
      for (int m = 0; m < 4; ++m) {
        float4 vq = *(const float4*)(&vs[s][cg*4 + m*32]);
        #pragma unroll
        for (int u = 0; u < 4; ++u) {
          acc[u][m*4+0] += wk[u]*vq.x;
          acc[u][m*4+1] += wk[u]*vq.y;
          acc[u][m*4+2] += wk[u]*vq.z;
          acc[u][m*4+3] += wk[u]*vq.w;
        }
      }
    }
  }
  float* dst = Dloc + ((size_t)bh*NCH + c) * (NB_DQK*NB_DH);
  #pragma unroll
  for (int u = 0; u < 4; ++u)
    #pragma unroll
    for (int m = 0; m < 4; ++m) {
      float4 o4 = { acc[u][m*4+0], acc[u][m*4+1], acc[u][m*4+2], acc[u][m*4+3] };
      *(float4*)(dst + (size_t)(i0+u)*NB_DH + cg*4 + m*32) = o4;
    }
}

// ---------------- sequential chunk-state combine ----------------
__global__ __launch_bounds__(256) void chunk_combine(
    const float* __restrict__ Dloc, const float* __restrict__ Gv,
    float* __restrict__ Cbef)
{
  const int bh = blockIdx.x, tid = threadIdx.x;
  float4 acc[8];
  #pragma unroll
  for (int p = 0; p < 8; ++p) acc[p] = float4{0.f,0.f,0.f,0.f};
  float Gprev = 0.f;
  for (int c = 0; c < NCH; ++c) {
    const float4* dl = (const float4*)(Dloc + ((size_t)bh*NCH + c)*8192);
    float4* cb = (float4*)(Cbef + ((size_t)bh*NCH + c)*8192);
    float Gend = Gv[bh*NB_S + c*CL + CL - 1];
    float decay = (c == 0) ? 0.f : expf(Gprev - Gend);
    #pragma unroll
    for (int p = 0; p < 8; ++p) {
      int idx = tid + p*256;
      cb[idx] = acc[p];
      float4 d = dl[idx];
      acc[p].x = acc[p].x*decay + d.x;
      acc[p].y = acc[p].y*decay + d.y;
      acc[p].z = acc[p].z*decay + d.z;
      acc[p].w = acc[p].w*decay + d.w;
    }
    Gprev = Gend;
  }
}

// ---------------- chunked attention + state + LN + gate -> hng (bf16) ----------------
__global__ __launch_bounds__(256,1) void chunk_out(
    const float* __restrict__ P,
    const float* __restrict__ gv, const float* __restrict__ Gv,
    const float* __restrict__ Cbef,
    const float* __restrict__ lnw, const float* __restrict__ lnb,
    unsigned short* __restrict__ hng)
{
  __shared__ float attT[128][132];
  __shared__ float buf[128][132];
  __shared__ float gsh[128], Gsh[128], rsh[128];

  const int bx = blockIdx.x, bh = bx >> 3, c = bx & 7;
  const int b = bh >> 3, h = bh & 7;
  const int tid = threadIdx.x;
  const int tr = tid >> 4, tc = tid & 15;
  const int t0 = tr * 8;
  const size_t rowbase = (size_t)b*NB_S + (size_t)c*CL;
  const int sgbase = bh*NB_S + c*CL;

  #pragma unroll
  for (int p = 0; p < 8; ++p) {
    int qd = tid + p*256;
    int t = qd >> 4, iq = qd & 15;
    float4 q4 = *(const float4*)(P + (rowbase + t)*LDP + h*NB_DQK + iq*4);
    buf[iq*4+0][t]=q4.x; buf[iq*4+1][t]=q4.y; buf[iq*4+2][t]=q4.z; buf[iq*4+3][t]=q4.w;
    float4 k4 = *(const float4*)(P + (rowbase + t)*LDP + 512 + h*NB_DQK + iq*4);
    buf[64+iq*4+0][t]=k4.x; buf[64+iq*4+1][t]=k4.y; buf[64+iq*4+2][t]=k4.z; buf[64+iq*4+3][t]=k4.w;
  }
  if (tid < 128) {
    float gval = gv[sgbase + tid];
    float Gval = Gv[sgbase + tid];
    gsh[tid] = gval; Gsh[tid] = Gval;
    float Gprev = (c > 0) ? Gv[sgbase - 1] : 0.f;
    rsh[tid] = 0.125f * expf(Gprev - Gval);
  }
  __syncthreads();

  auto mm = [&](float (&accR)[8][8], float (*Am)[132], int ar0,
                float (*Bm)[132], int br0, int nq) {
    for (int iq = 0; iq < nq; ++iq) {
      float a[4][8], bq[4][8];
      #pragma unroll
      for (int w = 0; w < 4; ++w) {
        const float* ap = Am[ar0 + iq*4 + w];
        *(float4*)(&a[w][0]) = *(const float4*)(ap + t0);
        *(float4*)(&a[w][4]) = *(const float4*)(ap + t0 + 4);
        const float* bp = Bm[br0 + iq*4 + w];
        *(float4*)(&bq[w][0]) = *(const float4*)(bp + tc*4);
        *(float4*)(&bq[w][4]) = *(const float4*)(bp + tc*4 + 64);
      }
      #pragma unroll
      for (int w = 0; w < 4; ++w)
        #pragma unroll
        for (int u = 0; u < 8; ++u)
          #pragma unroll
          for (int x = 0; x < 8; ++x)
            accR[u][x] += a[w][u]*bq[w][x];
    }
  };

  { // att = Q K^T, weight, mask, store transposed
    float accA[8][8] = {};
    mm(accA, buf, 0, buf, 64, 16);
    float gtv[8];
    #pragma unroll
    for (int u = 0; u < 8; ++u) gtv[u] = Gsh[t0 + u];
    #pragma unroll
    for (int x = 0; x < 8; ++x) {
      int s = tc*4 + (x>>2)*64 + (x&3);
      float gs = gsh[s];
      float vv[8];
      #pragma unroll
      for (int u = 0; u < 8; ++u) {
        int t = t0 + u;
        float w = 0.125f * expf(gs - gtv[u]);
        vv[u] = (s <= t) ? accA[u][x]*w : 0.f;
      }
      float4 lo = {vv[0],vv[1],vv[2],vv[3]}, hi = {vv[4],vv[5],vv[6],vv[7]};
      *(float4*)(&attT[s][t0])   = lo;
      *(float4*)(&attT[s][t0+4]) = hi;
    }
  }
  __syncthreads();

  { // load Cbefore into buf rows 64..127
    const float* Cbp = Cbef + ((size_t)bh*NCH + c)*(NB_DQK*NB_DH);
    #pragma unroll
    for (int p = 0; p < 8; ++p) {
      int qd = tid + p*256;
      int i = qd >> 5, jq = qd & 31;
      *(float4*)(&buf[64+i][jq*4]) = *(const float4*)(Cbp + (size_t)i*NB_DH + jq*4);
    }
  }
  __syncthreads();
  float acc2[8][8] = {};
  mm(acc2, buf, 0, buf, 64, 16);
  __syncthreads();

  { // load V into buf
    #pragma unroll
    for (int p = 0; p < 16; ++p) {
      int qd = tid + p*256;
      int sv = qd >> 5, jq = qd & 31;
      *(float4*)(&buf[sv][jq*4]) =
        *(const float4*)(P + (rowbase + sv)*LDP + 1024 + h*NB_DH + jq*4);
    }
  }
  __syncthreads();
  float hacc[8][8] = {};
  mm(hacc, attT, 0, buf, 0, 32);

  float lw[8], lb[8];
  {
    float4 a0 = *(const float4*)(lnw + h*NB_DH + tc*4);
    float4 a1 = *(const float4*)(lnw + h*NB_DH + tc*4 + 64);
    lw[0]=a0.x; lw[1]=a0.y; lw[2]=a0.z; lw[3]=a0.w;
    lw[4]=a1.x; lw[5]=a1.y; lw[6]=a1.z; lw[7]=a1.w;
    float4 b0 = *(const float4*)(lnb + h*NB_DH + tc*4);
    float4 b1 = *(const float4*)(lnb + h*NB_DH + tc*4 + 64);
    lb[0]=b0.x; lb[1]=b0.y; lb[2]=b0.z; lb[3]=b0.w;
    lb[4]=b1.x; lb[5]=b1.y; lb[6]=b1.z; lb[7]=b1.w;
  }
  #pragma unroll
  for (int u = 0; u < 8; ++u) {
    int t = t0 + u;
    float r = rsh[t];
    float hrow[8];
    #pragma unroll
    for (int x = 0; x < 8; ++x) hrow[x] = hacc[u][x] + r*acc2[u][x];
    float sum = 0.f, ssq = 0.f;
    #pragma unroll
    for (int x = 0; x < 8; ++x) { sum += hrow[x]; ssq += hrow[x]*hrow[x]; }
    #pragma unroll
    for (int off = 1; off < 16; off <<= 1) {
      sum += __shfl_xor(sum, off);
      ssq += __shfl_xor(ssq, off);
    }
    float mean = sum * (1.f/NB_DH);
    float var  = ssq * (1.f/NB_DH) - mean*mean;
    float rstd = rsqrtf(var + 1e-6f);
    #pragma unroll
    for (int m = 0; m < 2; ++m) {
      float4 xo = *(const float4*)(P + (rowbase + t)*LDP + 2048 + h*NB_DH + tc*4 + m*64);
      float xov[4] = {xo.x, xo.y, xo.z, xo.w};
      unsigned short res[4];
      #pragma unroll
      for (int w = 0; w < 4; ++w) {
        int x = m*4 + w;
        float hn = (hrow[x] - mean)*rstd*lw[x] + lb[x];
        float tt = tanhf(xov[w]*(1.f/15.f))*15.f;
        float o = 1.f/(1.f + expf(-tt));
        res[w] = f2bf(hn*o);
      }
      ushort4v r4 = {res[0],res[1],res[2],res[3]};
      *(ushort4v*)(hng + (rowbase + t)*1024 + h*NB_DH + tc*4 + m*64) = r4;
    }
  }
}

extern "C" void kernel_launch(void* const* d_in, const int* in_sizes, int n_in,
                              void* d_out, int out_size, void* d_ws, size_t ws_size,
                              hipStream_t stream)
{
  (void)in_sizes; (void)n_in; (void)out_size; (void)ws_size;
  const float* x   = (const float*)d_in[0];
  const float* Wq  = (const float*)d_in[1];
  const float* Wk  = (const float*)d_in[2];
  const float* Wv  = (const float*)d_in[3];
  const float* Wi  = (const float*)d_in[4];
  const float* bi  = (const float*)d_in[5];
  const float* Wf  = (const float*)d_in[6];
  const float* bf  = (const float*)d_in[7];
  const float* Wog = (const float*)d_in[8];
  const float* lnw = (const float*)d_in[9];
  const float* lnb = (const float*)d_in[10];
  const float* Wout= (const float*)d_in[11];
  float* out = (float*)d_out;
  float* ws  = (float*)d_ws;

  float*          Pp  = ws + OFF_P;
  unsigned short* xh  = (unsigned short*)(ws + OFF_XH);
  unsigned short* xl  = (unsigned short*)(ws + OFF_XL);
  unsigned short* Whi = (unsigned short*)(ws + OFF_WHI);
  unsigned short* Wlo = (unsigned short*)(ws + OFF_WLO);
  unsigned short* WtO = (unsigned short*)(ws + OFF_WTO);   // alias of Wlo (after proj)
  float*          iv  = ws + OFF_IV;
  float*          fv  = ws + OFF_FV;
  float*          g   = ws + OFF_G;
  float*          G   = ws + OFF_GM;
  float*          Dl  = ws + OFF_DL;                        // alias of xh
  float*          Cb  = ws + OFF_CB;                        // alias of Whi
  unsigned short* hng = (unsigned short*)(ws + OFF_HNG);    // alias of xl

  // input conversions: x -> (hi,lo); weights transposed -> B^T layout
  conv_split<<<1024, 256, 0, stream>>>(x, xh, xl, 2048*1024);
  transp_hl<<<dim3( 8,16), 256, 0, stream>>>(Wq,  Whi,              Wlo,             512);
  transp_hl<<<dim3( 8,16), 256, 0, stream>>>(Wk,  Whi +  512*1024,  Wlo + 512*1024,  512);
  transp_hl<<<dim3(16,16), 256, 0, stream>>>(Wv,  Whi + 1024*1024,  (unsigned short*)nullptr, 1024);
  transp_hl<<<dim3(16,16), 256, 0, stream>>>(Wog, Whi + 2048*1024,  (unsigned short*)nullptr, 1024);

  proj_if  <<<2048, 64, 0, stream>>>(x, Wi, bi, Wf, bf, iv, fv);
  gate_scan<<<16, 64, 0, stream>>>(iv, fv, g, G);

  // fused q|k|v|xog projection (split-bf16 precision on q,k columns)
  gemm_proj<<<dim3(24,16), 256, 0, stream>>>(xh, xl, Whi, Wlo, Pp);

  // Wout transpose reuses Wlo space (proj GEMM already consumed it)
  transp_hl<<<dim3(16,16), 256, 0, stream>>>(Wout, WtO, (unsigned short*)nullptr, 1024);

  chunk_local  <<<128, 128, 0, stream>>>(Pp, g, G, Dl);
  chunk_combine<<<16, 256, 0, stream>>>(Dl, G, Cb);
  chunk_out    <<<128, 256, 0, stream>>>(Pp, g, G, Cb, lnw, lnb, hng);

  // out = hng[2048x1024] x Wout[1024x1024]
  gemm_bf16<<<dim3(8,16), 256, 0, stream>>>(hng, WtO, out, 1024);
}

// Round 5
// 177.675 us; speedup vs baseline: 2.4986x; 1.1275x over previous
//
#include <hip/hip_runtime.h>
#include <math.h>

#define NB_B   2
#define NB_S   1024
#define NB_D   1024
#define NB_NH  8
#define NB_DQK 64
#define NB_DH  128
#define NCH    8
#define CL     128

typedef __attribute__((ext_vector_type(8))) short  short8v;   // 8 x bf16
typedef __attribute__((ext_vector_type(4))) float  f32x4;
typedef __attribute__((ext_vector_type(8))) unsigned short ushort8v;
typedef __attribute__((ext_vector_type(4))) unsigned short ushort4v;

__device__ __forceinline__ unsigned short f2bf(float f) {
  unsigned u = __float_as_uint(f);
  unsigned r = (u + 0x7FFFu + ((u >> 16) & 1u)) >> 16;
  return (unsigned short)r;
}
__device__ __forceinline__ float bf2f(unsigned short h) {
  return __uint_as_float(((unsigned)h) << 16);
}

#define GLD_LDS16(g, l) __builtin_amdgcn_global_load_lds( \
    (const __attribute__((address_space(1))) void*)(g),   \
    (__attribute__((address_space(3))) void*)(l), 16, 0, 0)

// ---------------- workspace offsets (floats) ----------------
constexpr size_t OFF_PQK = 0;                            // Pqk fp32 [2048][1024] = 2,097,152
constexpr size_t OFF_PVX = OFF_PQK + 2097152;            // Pvx fp32 [2048][2048] = 4,194,304
constexpr size_t OFF_XH  = OFF_PVX + 4194304;            // xh bf16 [2048][1024] -> 1,048,576 f
constexpr size_t OFF_XL  = OFF_XH  + 1048576;            // xl bf16 [2048][1024] -> 1,048,576 f
constexpr size_t OFF_WHI = OFF_XL  + 1048576;            // Whi bf16 [3072][1024] -> 1,572,864 f
constexpr size_t OFF_WLO = OFF_WHI + 1572864;            // Wlo bf16 [1024][1024] -> 524,288 f
constexpr size_t OFF_IV  = OFF_WLO + 524288;
constexpr size_t OFF_FV  = OFF_IV  + 16384;
constexpr size_t OFF_G   = OFF_FV  + 16384;
constexpr size_t OFF_GM  = OFF_G   + 16384;
// total 10,551,296 floats = 42.2 MB (same proven footprint)
// aliases (dead after gemm_proj):
constexpr size_t OFF_DL  = OFF_XH;                       // Dloc fp32 1,048,576
constexpr size_t OFF_HNG = OFF_XL;                       // hng bf16 [2048][1024] -> 1,048,576 f
constexpr size_t OFF_CB  = OFF_WHI;                      // Cbef fp32 1,048,576 (<= Whi region)
constexpr size_t OFF_WTO = OFF_WLO;                      // WtO bf16 [1024][1024]

// ---------------- fp32 -> (hi,lo) bf16 split ----------------
__global__ __launch_bounds__(256) void conv_split(
    const float* __restrict__ src,
    unsigned short* __restrict__ hi, unsigned short* __restrict__ lo, int n)
{
  int i = (blockIdx.x * 256 + threadIdx.x) * 8;
  if (i >= n) return;
  float4 a = *(const float4*)(src + i);
  float4 b = *(const float4*)(src + i + 4);
  float v[8] = { a.x, a.y, a.z, a.w, b.x, b.y, b.z, b.w };
  ushort8v rh, rl;
  #pragma unroll
  for (int j = 0; j < 8; ++j) {
    unsigned short h = f2bf(v[j]);
    rh[j] = h;
    rl[j] = f2bf(v[j] - bf2f(h));
  }
  *(ushort8v*)(hi + i) = rh;
  *(ushort8v*)(lo + i) = rl;
}

// ---------------- transpose + convert core ----------------
__device__ __forceinline__ void transp_body(
    const float* __restrict__ src,
    unsigned short* __restrict__ hi, unsigned short* __restrict__ lo,
    int N, int nt, int kt, int tid, float (*Ls)[65])
{
  #pragma unroll
  for (int p = 0; p < 16; ++p) {
    int lin = p * 256 + tid;
    int kr = lin >> 6, nc = lin & 63;
    Ls[kr][nc] = src[(size_t)(kt*64 + kr) * N + nt*64 + nc];
  }
  __syncthreads();
  #pragma unroll
  for (int p = 0; p < 16; ++p) {
    int lin = p * 256 + tid;
    int nr = lin >> 6, kc = lin & 63;
    float v = Ls[kc][nr];
    unsigned short h = f2bf(v);
    size_t di = (size_t)(nt*64 + nr) * 1024 + kt*64 + kc;
    hi[di] = h;
    if (lo) lo[di] = f2bf(v - bf2f(h));
  }
}

// merged transpose of Wq,Wk,Wv,Wog (grid.x = 8+8+16+16 = 48)
__global__ __launch_bounds__(256) void transp4(
    const float* __restrict__ Wq, const float* __restrict__ Wk,
    const float* __restrict__ Wv, const float* __restrict__ Wog,
    unsigned short* __restrict__ Whi, unsigned short* __restrict__ Wlo)
{
  __shared__ float Ls[64][65];
  const int x = blockIdx.x, kt = blockIdx.y, tid = threadIdx.x;
  if (x < 8)       transp_body(Wq,  Whi,              Wlo,            512,  x,      kt, tid, Ls);
  else if (x < 16) transp_body(Wk,  Whi +  512*1024,  Wlo + 512*1024, 512,  x - 8,  kt, tid, Ls);
  else if (x < 32) transp_body(Wv,  Whi + 1024*1024,  nullptr,        1024, x - 16, kt, tid, Ls);
  else             transp_body(Wog, Whi + 2048*1024,  nullptr,        1024, x - 32, kt, tid, Ls);
}

// single transpose (Wout, runs after gemm_proj frees Wlo space)
__global__ __launch_bounds__(256) void transp_hl(
    const float* __restrict__ src,
    unsigned short* __restrict__ hi, int N)
{
  __shared__ float Ls[64][65];
  transp_body(src, hi, nullptr, N, blockIdx.x, blockIdx.y, threadIdx.x, Ls);
}

// ---------------- fused projection GEMM, uniform 16-kt blocks ----------------
// grid.x = 40: ct 0..7  : xh*Whi  -> Pqk (atomic)
//              ct 8..23 : xh*Whi  -> Pvx (store)   [v: 8..15, xog: 16..23]
//              ct 24..31: xl*Whi  -> Pqk (atomic)
//              ct 32..39: xh*Wlo  -> Pqk (atomic)
__global__ __launch_bounds__(256) void gemm_proj(
    const unsigned short* __restrict__ xh,
    const unsigned short* __restrict__ xl,
    const unsigned short* __restrict__ Whi,
    const unsigned short* __restrict__ Wlo,
    float* __restrict__ Pqk, float* __restrict__ Pvx)
{
  __shared__ __align__(16) unsigned short As[128*64];
  __shared__ __align__(16) unsigned short Bs[128*64];
  const int tid  = threadIdx.x;
  const int ct   = blockIdx.x, bm = blockIdx.y;
  const int wid  = tid >> 6, lane = tid & 63;
  const int wm   = wid >> 1, wn = wid & 1;
  const int lrow = lane & 15;
  const int lk   = (lane >> 4) * 16;

  const unsigned short* Ap; const unsigned short* Bp;
  float* Cp; int ldc, colb; bool atom;
  if (ct < 8)       { Ap=xh; Bp=Whi + (size_t)ct*128*1024;      Cp=Pqk; ldc=1024; colb=ct*128;      atom=true;  }
  else if (ct < 24) { Ap=xh; Bp=Whi + (size_t)ct*128*1024;      Cp=Pvx; ldc=2048; colb=(ct-8)*128;  atom=false; }
  else if (ct < 32) { Ap=xl; Bp=Whi + (size_t)(ct-24)*128*1024; Cp=Pqk; ldc=1024; colb=(ct-24)*128; atom=true;  }
  else              { Ap=xh; Bp=Wlo + (size_t)(ct-32)*128*1024; Cp=Pqk; ldc=1024; colb=(ct-32)*128; atom=true;  }

  f32x4 acc[4][4];
  const f32x4 z4 = { 0.f, 0.f, 0.f, 0.f };
  #pragma unroll
  for (int m = 0; m < 4; ++m)
    #pragma unroll
    for (int n = 0; n < 4; ++n) acc[m][n] = z4;

  const int srow = tid >> 3;
  const int scb  = (tid & 7) << 4;
  size_t gAo[4], gBo[4];
  #pragma unroll
  for (int i = 0; i < 4; ++i) {
    int row = i * 32 + srow;
    int cbs = scb ^ ((row & 7) << 4);
    gAo[i] = (size_t)(bm*128 + row) * 2048 + cbs;
    gBo[i] = (size_t)row * 2048 + cbs;
  }
  const int ldsW = wid * 1024;
  const char* Ab = (const char*)Ap;
  const char* Bb = (const char*)Bp;

  for (int kt = 0; kt < 16; ++kt) {
    __syncthreads();
    #pragma unroll
    for (int i = 0; i < 4; ++i)
      GLD_LDS16(Ab + gAo[i] + kt*128, (char*)As + i*4096 + ldsW);
    #pragma unroll
    for (int i = 0; i < 4; ++i)
      GLD_LDS16(Bb + gBo[i] + kt*128, (char*)Bs + i*4096 + ldsW);
    __syncthreads();

    #pragma unroll
    for (int kk = 0; kk < 2; ++kk) {
      short8v a[4], b[4];
      #pragma unroll
      for (int m = 0; m < 4; ++m) {
        int row = wm*64 + m*16 + lrow;
        int kb  = (kk*64 + lk) ^ ((row & 7) << 4);
        a[m] = *(const short8v*)((const char*)As + row*128 + kb);
      }
      #pragma unroll
      for (int n = 0; n < 4; ++n) {
        int row = wn*64 + n*16 + lrow;
        int kb  = (kk*64 + lk) ^ ((row & 7) << 4);
        b[n] = *(const short8v*)((const char*)Bs + row*128 + kb);
      }
      #pragma unroll
      for (int m = 0; m < 4; ++m)
        #pragma unroll
        for (int n = 0; n < 4; ++n)
          acc[m][n] = __builtin_amdgcn_mfma_f32_16x16x32_bf16(a[m], b[n], acc[m][n], 0, 0, 0);
    }
  }

  const int crow0 = bm*128 + wm*64 + ((lane >> 4) << 2);
  const int ccol0 = colb + wn*64 + (lane & 15);
  if (atom) {
    #pragma unroll
    for (int m = 0; m < 4; ++m)
      #pragma unroll
      for (int n = 0; n < 4; ++n)
        #pragma unroll
        for (int r = 0; r < 4; ++r)
          unsafeAtomicAdd(&Cp[(size_t)(crow0 + m*16 + r) * ldc + ccol0 + n*16], acc[m][n][r]);
  } else {
    #pragma unroll
    for (int m = 0; m < 4; ++m)
      #pragma unroll
      for (int n = 0; n < 4; ++n)
        #pragma unroll
        for (int r = 0; r < 4; ++r)
          Cp[(size_t)(crow0 + m*16 + r) * ldc + ccol0 + n*16] = acc[m][n][r];
  }
}

// ---------------- output GEMM: 128x64 tiles ----------------
__global__ __launch_bounds__(256) void gemm_out64(
    const unsigned short* __restrict__ A,
    const unsigned short* __restrict__ Bt,
    float* __restrict__ C, int ldc)
{
  __shared__ __align__(16) unsigned short As[128*64];
  __shared__ __align__(16) unsigned short Bs[64*64];
  const int tid  = threadIdx.x;
  const int bm   = blockIdx.y, cn = blockIdx.x;
  const int wid  = tid >> 6, lane = tid & 63;
  const int wm   = wid >> 1, wn = wid & 1;
  const int lrow = lane & 15;
  const int lk   = (lane >> 4) * 16;

  f32x4 acc[4][2];
  const f32x4 z4 = { 0.f, 0.f, 0.f, 0.f };
  #pragma unroll
  for (int m = 0; m < 4; ++m)
    #pragma unroll
    for (int n = 0; n < 2; ++n) acc[m][n] = z4;

  const int srow = tid >> 3;
  const int scb  = (tid & 7) << 4;
  const char* Ab = (const char*)A;
  const char* Bb = (const char*)Bt;
  size_t gA[4], gB[2];
  #pragma unroll
  for (int i = 0; i < 4; ++i) {
    int row = i * 32 + srow;
    int cbs = scb ^ ((row & 7) << 4);
    gA[i] = (size_t)(bm*128 + row) * 2048 + cbs;
  }
  #pragma unroll
  for (int i = 0; i < 2; ++i) {
    int row = i * 32 + srow;
    int cbs = scb ^ ((row & 7) << 4);
    gB[i] = (size_t)(cn*64 + row) * 2048 + cbs;
  }
  const int ldsW = wid * 1024;

  for (int kt = 0; kt < 16; ++kt) {
    __syncthreads();
    #pragma unroll
    for (int i = 0; i < 4; ++i)
      GLD_LDS16(Ab + gA[i] + kt*128, (char*)As + i*4096 + ldsW);
    #pragma unroll
    for (int i = 0; i < 2; ++i)
      GLD_LDS16(Bb + gB[i] + kt*128, (char*)Bs + i*4096 + ldsW);
    __syncthreads();

    #pragma unroll
    for (int kk = 0; kk < 2; ++kk) {
      short8v a[4], b[2];
      #pragma unroll
      for (int m = 0; m < 4; ++m) {
        int row = wm*64 + m*16 + lrow;
        int kb  = (kk*64 + lk) ^ ((row & 7) << 4);
        a[m] = *(const short8v*)((const char*)As + row*128 + kb);
      }
      #pragma unroll
      for (int n = 0; n < 2; ++n) {
        int row = wn*32 + n*16 + lrow;
        int kb  = (kk*64 + lk) ^ ((row & 7) << 4);
        b[n] = *(const short8v*)((const char*)Bs + row*128 + kb);
      }
      #pragma unroll
      for (int m = 0; m < 4; ++m)
        #pragma unroll
        for (int n = 0; n < 2; ++n)
          acc[m][n] = __builtin_amdgcn_mfma_f32_16x16x32_bf16(a[m], b[n], acc[m][n], 0, 0, 0);
    }
  }

  const int crow0 = bm*128 + wm*64 + ((lane >> 4) << 2);
  const int ccol0 = cn*64 + wn*32 + (lane & 15);
  #pragma unroll
  for (int m = 0; m < 4; ++m)
    #pragma unroll
    for (int n = 0; n < 2; ++n)
      #pragma unroll
      for (int r = 0; r < 4; ++r)
        C[(size_t)(crow0 + m*16 + r) * ldc + ccol0 + n*16] = acc[m][n][r];
}

// ---------------- i/f projections (fp32, skinny N=8) ----------------
__global__ __launch_bounds__(64) void proj_if(
    const float* __restrict__ x,
    const float* __restrict__ Wi, const float* __restrict__ bi,
    const float* __restrict__ Wf, const float* __restrict__ bf,
    float* __restrict__ iv, float* __restrict__ fv)
{
  const int row = blockIdx.x, l = threadIdx.x;
  const float* xr = x + (size_t)row * NB_D;
  float ai[8] = {}, af[8] = {};
  for (int p = 0; p < 16; ++p) {
    int kk = l + p * 64;
    float xv = xr[kk];
    const float* wi = Wi + (size_t)kk * NB_NH;
    const float* wf = Wf + (size_t)kk * NB_NH;
    #pragma unroll
    for (int cc = 0; cc < 8; ++cc) { ai[cc] += xv*wi[cc]; af[cc] += xv*wf[cc]; }
  }
  #pragma unroll
  for (int off = 1; off < 64; off <<= 1) {
    #pragma unroll
    for (int cc = 0; cc < 8; ++cc) {
      ai[cc] += __shfl_xor(ai[cc], off);
      af[cc] += __shfl_xor(af[cc], off);
    }
  }
  if (l == 0) {
    int b = row >> 10, s = row & (NB_S - 1);
    #pragma unroll
    for (int cc = 0; cc < 8; ++cc) {
      iv[(size_t)(b*NB_NH + cc) * NB_S + s] = ai[cc] + bi[cc];
      fv[(size_t)(b*NB_NH + cc) * NB_S + s] = af[cc] + bf[cc];
    }
  }
}

// ---------------- gate scan ----------------
__global__ __launch_bounds__(64) void gate_scan(
    const float* __restrict__ iv, const float* __restrict__ fv,
    float* __restrict__ gv, float* __restrict__ Gv)
{
  const int bh = blockIdx.x, l = threadIdx.x;
  const int base = bh * NB_S + l * 16;
  float fl[16];
  float run = 0.f;
  #pragma unroll
  for (int u = 0; u < 16; ++u) {
    float fr = fv[base + u];
    float flog = (fr >= 0.f) ? -log1pf(expf(-fr)) : (fr - log1pf(expf(fr)));
    run += flog; fl[u] = run;
  }
  float tot = run, sc = tot;
  #pragma unroll
  for (int off = 1; off < 64; off <<= 1) {
    float t = __shfl_up(sc, off);
    if (l >= off) sc += t;
  }
  float excl = sc - tot;
  float gm[16]; float rmax = -1e30f;
  #pragma unroll
  for (int u = 0; u < 16; ++u) {
    float bt = excl + fl[u];
    float g = iv[base + u] - bt;
    gv[base + u] = g;
    rmax = fmaxf(rmax, g); gm[u] = rmax;
  }
  float mx = rmax;
  #pragma unroll
  for (int off = 1; off < 64; off <<= 1) {
    float t = __shfl_up(mx, off);
    if (l >= off) mx = fmaxf(mx, t);
  }
  float em = __shfl_up(mx, 1);
  if (l == 0) em = -1e30f;
  #pragma unroll
  for (int u = 0; u < 16; ++u)
    Gv[base + u] = fmaxf(0.f, fmaxf(em, gm[u]));
}

// ---------------- per-chunk local KV state ----------------
__global__ __launch_bounds__(128) void chunk_local(
    const float* __restrict__ Pqk, const float* __restrict__ Pvx,
    const float* __restrict__ gv, const float* __restrict__ Gv,
    float* __restrict__ Dloc)
{
  __shared__ float ks[16][68];
  __shared__ float vs[16][132];
  __shared__ float wsg[16];
  const int bx = blockIdx.x, bh = bx >> 3, c = bx & 7;
  const int b = bh >> 3, h = bh & 7;
  const int tid = threadIdx.x;
  const int rg = tid >> 3, cg = tid & 7;
  const int i0 = rg * 4;
  float acc[4][16] = {};
  const float Gend = Gv[bh*NB_S + c*CL + CL - 1];
  const float* kbp = Pqk + ((size_t)b*NB_S + c*CL) * 1024 + 512 + h*NB_DQK;
  const float* vbp = Pvx + ((size_t)b*NB_S + c*CL) * 2048 + h*NB_DH;
  const float* gbp = gv + bh*NB_S + c*CL;
  for (int sb = 0; sb < 8; ++sb) {
    __syncthreads();
    #pragma unroll
    for (int p = 0; p < 2; ++p) {
      int qd = tid + p*128; int r = qd >> 4, cq = qd & 15;
      *(float4*)(&ks[r][cq*4]) = *(const float4*)(kbp + (size_t)(sb*16 + r)*1024 + cq*4);
    }
    #pragma unroll
    for (int p = 0; p < 4; ++p) {
      int qd = tid + p*128; int r = qd >> 5, cq = qd & 31;
      *(float4*)(&vs[r][cq*4]) = *(const float4*)(vbp + (size_t)(sb*16 + r)*2048 + cq*4);
    }
    if (tid < 16) wsg[tid] = expf(gbp[sb*16 + tid] - Gend);
    __syncthreads();
    #pragma unroll
    for (int s = 0; s < 16; ++s) {
      float w = wsg[s];
      float4 kq = *(const float4*)(&ks[s][i0]);
      float wk[4] = { w*kq.x, w*kq.y, w*kq.z, w*kq.w };
      #pragma unroll
      for (int m = 0; m < 4; ++m) {
        float4 vq = *(const float4*)(&vs[s][cg*4 + m*32]);
        #pragma unroll
        for (int u = 0; u < 4; ++u) {
          acc[u][m*4+0] += wk[u]*vq.x;
          acc[u][m*4+1] += wk[u]*vq.y;
          acc[u][m*4+2] += wk[u]*vq.z;
          acc[u][m*4+3] += wk[u]*vq.w;
        }
      }
    }
  }
  float* dst = Dloc + ((size_t)bh*NCH + c) * (NB_DQK*NB_DH);
  #pragma unroll
  for (int u = 0; u < 4; ++u)
    #pragma unroll
    for (int m = 0; m < 4; ++m) {
      float4 o4 = { acc[u][m*4+0], acc[u][m*4+1], acc[u][m*4+2], acc[u][m*4+3] };
      *(float4*)(dst + (size_t)(i0+u)*NB_DH + cg*4 + m*32) = o4;
    }
}

// ---------------- sequential chunk-state combine ----------------
__global__ __launch_bounds__(256) void chunk_combine(
    const float* __restrict__ Dloc, const float* __restrict__ Gv,
    float* __restrict__ Cbef)
{
  const int bh = blockIdx.x, tid = threadIdx.x;
  float4 acc[8];
  #pragma unroll
  for (int p = 0; p < 8; ++p) acc[p] = float4{0.f,0.f,0.f,0.f};
  float Gprev = 0.f;
  for (int c = 0; c < NCH; ++c) {
    const float4* dl = (const float4*)(Dloc + ((size_t)bh*NCH + c)*8192);
    float4* cb = (float4*)(Cbef + ((size_t)bh*NCH + c)*8192);
    float Gend = Gv[bh*NB_S + c*CL + CL - 1];
    float decay = (c == 0) ? 0.f : expf(Gprev - Gend);
    #pragma unroll
    for (int p = 0; p < 8; ++p) {
      int idx = tid + p*256;
      cb[idx] = acc[p];
      float4 d = dl[idx];
      acc[p].x = acc[p].x*decay + d.x;
      acc[p].y = acc[p].y*decay + d.y;
      acc[p].z = acc[p].z*decay + d.z;
      acc[p].w = acc[p].w*decay + d.w;
    }
    Gprev = Gend;
  }
}

// ---------------- chunked attention + state + LN + gate -> hng (bf16) ----------------
// grid 256: bh(16) x c(8) x half(2); each block computes 64 t-rows of one chunk.
__global__ __launch_bounds__(256,1) void chunk_out(
    const float* __restrict__ Pqk, const float* __restrict__ Pvx,
    const float* __restrict__ gv, const float* __restrict__ Gv,
    const float* __restrict__ Cbef,
    const float* __restrict__ lnw, const float* __restrict__ lnb,
    unsigned short* __restrict__ hng)
{
  __shared__ float attT[128][132];
  __shared__ float buf[128][132];
  __shared__ float gsh[128], Gsh[128], rsh[128];

  const int bx = blockIdx.x;
  const int half = bx & 1, c = (bx >> 1) & 7, bh = bx >> 4;
  const int b = bh >> 3, h = bh & 7;
  const int tid = threadIdx.x;
  const int tr = tid >> 4, tc = tid & 15;
  const int t0 = half*64 + tr*4;
  const size_t rowbase = (size_t)b*NB_S + (size_t)c*CL;
  const int sgbase = bh*NB_S + c*CL;

  #pragma unroll
  for (int p = 0; p < 8; ++p) {
    int qd = tid + p*256;
    int t = qd >> 4, iq = qd & 15;
    float4 q4 = *(const float4*)(Pqk + (rowbase + t)*1024 + h*NB_DQK + iq*4);
    buf[iq*4+0][t]=q4.x; buf[iq*4+1][t]=q4.y; buf[iq*4+2][t]=q4.z; buf[iq*4+3][t]=q4.w;
    float4 k4 = *(const float4*)(Pqk + (rowbase + t)*1024 + 512 + h*NB_DQK + iq*4);
    buf[64+iq*4+0][t]=k4.x; buf[64+iq*4+1][t]=k4.y; buf[64+iq*4+2][t]=k4.z; buf[64+iq*4+3][t]=k4.w;
  }
  if (tid < 128) {
    float gval = gv[sgbase + tid];
    float Gval = Gv[sgbase + tid];
    gsh[tid] = gval; Gsh[tid] = Gval;
    float Gprev = (c > 0) ? Gv[sgbase - 1] : 0.f;
    rsh[tid] = 0.125f * expf(Gprev - Gval);
  }
  __syncthreads();

  auto mm = [&](float (&accR)[4][8], float (*Am)[132], int ar0,
                float (*Bm)[132], int br0, int nq) {
    for (int iq = 0; iq < nq; ++iq) {
      float a[4][4], bq[4][8];
      #pragma unroll
      for (int w = 0; w < 4; ++w) {
        const float* ap = Am[ar0 + iq*4 + w];
        *(float4*)(&a[w][0]) = *(const float4*)(ap + t0);
        const float* bp = Bm[br0 + iq*4 + w];
        *(float4*)(&bq[w][0]) = *(const float4*)(bp + tc*4);
        *(float4*)(&bq[w][4]) = *(const float4*)(bp + tc*4 + 64);
      }
      #pragma unroll
      for (int w = 0; w < 4; ++w)
        #pragma unroll
        for (int u = 0; u < 4; ++u)
          #pragma unroll
          for (int x = 0; x < 8; ++x)
            accR[u][x] += a[w][u]*bq[w][x];
    }
  };

  { // att = Q K^T, weight, mask, store transposed (all 128 s rows written)
    float accA[4][8] = {};
    mm(accA, buf, 0, buf, 64, 16);
    float gtv[4];
    #pragma unroll
    for (int u = 0; u < 4; ++u) gtv[u] = Gsh[t0 + u];
    #pragma unroll
    for (int x = 0; x < 8; ++x) {
      int s = tc*4 + (x>>2)*64 + (x&3);
      float gs = gsh[s];
      float vv[4];
      #pragma unroll
      for (int u = 0; u < 4; ++u) {
        int t = t0 + u;
        float w = 0.125f * expf(gs - gtv[u]);
        vv[u] = (s <= t) ? accA[u][x]*w : 0.f;
      }
      float4 lo = {vv[0],vv[1],vv[2],vv[3]};
      *(float4*)(&attT[s][t0]) = lo;
    }
  }
  __syncthreads();

  { // load Cbefore into buf rows 64..127
    const float* Cbp = Cbef + ((size_t)bh*NCH + c)*(NB_DQK*NB_DH);
    #pragma unroll
    for (int p = 0; p < 8; ++p) {
      int qd = tid + p*256;
      int i = qd >> 5, jq = qd & 31;
      *(float4*)(&buf[64+i][jq*4]) = *(const float4*)(Cbp + (size_t)i*NB_DH + jq*4);
    }
  }
  __syncthreads();
  float acc2[4][8] = {};
  mm(acc2, buf, 0, buf, 64, 16);
  __syncthreads();

  { // load V into buf
    #pragma unroll
    for (int p = 0; p < 16; ++p) {
      int qd = tid + p*256;
      int sv = qd >> 5, jq = qd & 31;
      *(float4*)(&buf[sv][jq*4]) =
        *(const float4*)(Pvx + (rowbase + sv)*2048 + h*NB_DH + jq*4);
    }
  }
  __syncthreads();
  float hacc[4][8] = {};
  mm(hacc, attT, 0, buf, 0, 32);

  float lw[8], lb[8];
  {
    float4 a0 = *(const float4*)(lnw + h*NB_DH + tc*4);
    float4 a1 = *(const float4*)(lnw + h*NB_DH + tc*4 + 64);
    lw[0]=a0.x; lw[1]=a0.y; lw[2]=a0.z; lw[3]=a0.w;
    lw[4]=a1.x; lw[5]=a1.y; lw[6]=a1.z; lw[7]=a1.w;
    float4 b0 = *(const float4*)(lnb + h*NB_DH + tc*4);
    float4 b1 = *(const float4*)(lnb + h*NB_DH + tc*4 + 64);
    lb[0]=b0.x; lb[1]=b0.y; lb[2]=b0.z; lb[3]=b0.w;
    lb[4]=b1.x; lb[5]=b1.y; lb[6]=b1.z; lb[7]=b1.w;
  }
  #pragma unroll
  for (int u = 0; u < 4; ++u) {
    int t = t0 + u;
    float r = rsh[t];
    float hrow[8];
    #pragma unroll
    for (int x = 0; x < 8; ++x) hrow[x] = hacc[u][x] + r*acc2[u][x];
    float sum = 0.f, ssq = 0.f;
    #pragma unroll
    for (int x = 0; x < 8; ++x) { sum += hrow[x]; ssq += hrow[x]*hrow[x]; }
    #pragma unroll
    for (int off = 1; off < 16; off <<= 1) {
      sum += __shfl_xor(sum, off);
      ssq += __shfl_xor(ssq, off);
    }
    float mean = sum * (1.f/NB_DH);
    float var  = ssq * (1.f/NB_DH) - mean*mean;
    float rstd = rsqrtf(var + 1e-6f);
    #pragma unroll
    for (int m = 0; m < 2; ++m) {
      float4 xo = *(const float4*)(Pvx + (rowbase + t)*2048 + 1024 + h*NB_DH + tc*4 + m*64);
      float xov[4] = {xo.x, xo.y, xo.z, xo.w};
      unsigned short res[4];
      #pragma unroll
      for (int w = 0; w < 4; ++w) {
        int x = m*4 + w;
        float hn = (hrow[x] - mean)*rstd*lw[x] + lb[x];
        float tt = tanhf(xov[w]*(1.f/15.f))*15.f;
        float o = 1.f/(1.f + expf(-tt));
        res[w] = f2bf(hn*o);
      }
      ushort4v r4 = {res[0],res[1],res[2],res[3]};
      *(ushort4v*)(hng + (rowbase + t)*1024 + h*NB_DH + tc*4 + m*64) = r4;
    }
  }
}

extern "C" void kernel_launch(void* const* d_in, const int* in_sizes, int n_in,
                              void* d_out, int out_size, void* d_ws, size_t ws_size,
                              hipStream_t stream)
{
  (void)in_sizes; (void)n_in; (void)out_size; (void)ws_size;
  const float* x   = (const float*)d_in[0];
  const float* Wq  = (const float*)d_in[1];
  const float* Wk  = (const float*)d_in[2];
  const float* Wv  = (const float*)d_in[3];
  const float* Wi  = (const float*)d_in[4];
  const float* bi  = (const float*)d_in[5];
  const float* Wf  = (const float*)d_in[6];
  const float* bf  = (const float*)d_in[7];
  const float* Wog = (const float*)d_in[8];
  const float* lnw = (const float*)d_in[9];
  const float* lnb = (const float*)d_in[10];
  const float* Wout= (const float*)d_in[11];
  float* out = (float*)d_out;
  float* ws  = (float*)d_ws;

  float*          Pqk = ws + OFF_PQK;
  float*          Pvx = ws + OFF_PVX;
  unsigned short* xh  = (unsigned short*)(ws + OFF_XH);
  unsigned short* xl  = (unsigned short*)(ws + OFF_XL);
  unsigned short* Whi = (unsigned short*)(ws + OFF_WHI);
  unsigned short* Wlo = (unsigned short*)(ws + OFF_WLO);
  unsigned short* WtO = (unsigned short*)(ws + OFF_WTO);   // alias of Wlo (after proj)
  float*          iv  = ws + OFF_IV;
  float*          fv  = ws + OFF_FV;
  float*          g   = ws + OFF_G;
  float*          G   = ws + OFF_GM;
  float*          Dl  = ws + OFF_DL;                        // alias of xh
  float*          Cb  = ws + OFF_CB;                        // alias of Whi
  unsigned short* hng = (unsigned short*)(ws + OFF_HNG);    // alias of xl

  // zero the atomic-accumulated q,k buffer (graph-capturable, replay-safe)
  hipMemsetAsync(Pqk, 0, 2048ull*1024*sizeof(float), stream);

  conv_split<<<1024, 256, 0, stream>>>(x, xh, xl, 2048*1024);
  transp4   <<<dim3(48,16), 256, 0, stream>>>(Wq, Wk, Wv, Wog, Whi, Wlo);

  proj_if  <<<2048, 64, 0, stream>>>(x, Wi, bi, Wf, bf, iv, fv);
  gate_scan<<<16, 64, 0, stream>>>(iv, fv, g, G);

  // uniform-cost fused projection (atomic split-bf16 accumulation for q,k)
  gemm_proj<<<dim3(40,16), 256, 0, stream>>>(xh, xl, Whi, Wlo, Pqk, Pvx);

  // Wout transpose reuses Wlo space (gemm_proj already consumed it)
  transp_hl<<<dim3(16,16), 256, 0, stream>>>(Wout, WtO, 1024);

  chunk_local  <<<128, 128, 0, stream>>>(Pqk, Pvx, g, G, Dl);
  chunk_combine<<<16, 256, 0, stream>>>(Dl, G, Cb);
  chunk_out    <<<256, 256, 0, stream>>>(Pqk, Pvx, g, G, Cb, lnw, lnb, hng);

  // out = hng[2048x1024] x Wout[1024x1024]
  gemm_out64<<<dim3(16,16), 256, 0, stream>>>(hng, WtO, out, 1024);
}